// Round 8
// baseline (232.752 us; speedup 1.0000x reference)
//
#include <hip/hip_runtime.h>

// DVDNMixer: 8-fold PMF convolution (51 atoms -> 401) + C51 projection to 51.
//
// Projection is exact-integer: support=linspace(-80,80,401), delta=0.4 =>
//   out[0] = sum q[0..175]; out[j] = q[175+j] (1<=j<=49); out[50] = sum q[225..400]
//
// One wave per (b,t) task; per-wave zero-padded LDS ping-pong buffers. Waves
// are fully independent: NO __syncthreads and NO explicit waitcnt — per-wave
// LDS RAW is safe because DS ops from one wave execute in order, and the
// volatile qualifier forbids the compiler from reordering the next step's
// reads above this step's writes (volatile-volatile order). The compiler
// inserts counted lgkmcnt(N) waits only where FMAs consume loaded data.
// (R3 post-mortem: an explicit lgkmcnt(0)+memory-clobber per step serialized
// scalar p-loads with LDS and capped VALUBusy at 57%.)
//
// Layout is LINEAR (R3's holed layout cost ~45 addr-VALU ops/step; linear
// needs one base address + offset: immediates). Conflicts: R=4 window reads
// are 2-way (free per m136), R=8 are 4-way (1.58x, hidden under 816cy FMA).
//
//   - window loads are VOLATILE float4 LDS reads => ds_read_b128, window
//     pinned in VGPRs (R1 post-mortem: non-volatile was rematerialized into
//     per-use ds_read_b32: VGPR=36, 9.7e7 conflict cycles)
//   - p[j] is wave-uniform (readfirstlane'd task) => scalar s_load => FMA
//     with SGPR operand; free to pipeline across steps
//   - outputs beyond L_out compute to exact zeros (zero-padded windows), so
//     writes are unguarded; zero-invariants hold inductively.
// Step 7 keeps results in registers and feeds the projection directly.

typedef float f4 __attribute__((ext_vector_type(4)));

#define N_ATOM  51
#define N_TASKS 32768            // BS*T = 128*256
#define WPB     4
#define PAD     52               // left zero pad, floats (16B multiple)
#define BUFSZ   576              // floats; max read = lane63,R=8: 504+60=564

// acc[0..R) = conv outputs at positions lane*R + r of (q_in (*) p).
// q[k] at bin[PAD+k]; window W[x] = bin[lane*R + x]; FMA uses W[PAD+r-j],
// index range [2, R+51] within [0, 4*NW).
template<int R>
__device__ __forceinline__ void conv_body(const float* __restrict__ gp,
                                          const float* bin, float* acc, int lane) {
  constexpr int NW = (R + PAD) / 4;          // 14 (R=4) / 15 (R=8)
  const int o0 = lane * R;                   // 16B-aligned (R%4==0)
  float W[NW * 4];
#pragma unroll
  for (int m = 0; m < NW; ++m) {
    f4 v = *(const volatile f4*)(bin + o0 + 4 * m);   // one base + offset:
    W[4 * m + 0] = v.x; W[4 * m + 1] = v.y;
    W[4 * m + 2] = v.z; W[4 * m + 3] = v.w;
  }
  float p[N_ATOM];                           // uniform addr -> s_load -> SGPRs
#pragma unroll
  for (int j = 0; j < N_ATOM; ++j) p[j] = gp[j];
#pragma unroll
  for (int r = 0; r < R; ++r) acc[r] = 0.f;
#pragma unroll
  for (int j = 0; j < N_ATOM; ++j)
#pragma unroll
    for (int r = 0; r < R; ++r)
      acc[r] = fmaf(p[j], W[PAD + r - j], acc[r]);
}

template<int R>
__device__ __forceinline__ void conv_step(const float* __restrict__ gp,
                                          const float* bin, float* bout, int lane) {
  float acc[R];
  conv_body<R>(gp, bin, acc, lane);
#pragma unroll
  for (int r4 = 0; r4 < R / 4; ++r4) {
    f4 v = { acc[4 * r4 + 0], acc[4 * r4 + 1], acc[4 * r4 + 2], acc[4 * r4 + 3] };
    *(volatile f4*)(bout + PAD + lane * R + 4 * r4) = v;
  }
}

__global__ __launch_bounds__(256)
void dvdn_mixer_kernel(const float* __restrict__ in, float* __restrict__ out) {
  __shared__ __align__(16) float buf[WPB][2][BUFSZ];
  const int lane = threadIdx.x & 63;
  const int wave = threadIdx.x >> 6;
  const int task = __builtin_amdgcn_readfirstlane(blockIdx.x * WPB + wave);

  const float* gp = in + (size_t)task * (8 * N_ATOM);
  float* b0 = buf[wave][0];
  float* b1 = buf[wave][1];

  // Init b0 = {zeros, agent0 at [PAD,PAD+51)}. Regions of b0 beyond
  // [PAD,PAD+256) are never re-written by R=4 steps, so init zeros serve
  // steps 5/7's wider windows (step6 R=8 rewrites [PAD,PAD+512) before
  // step7 reads; [PAD+512,576) stays init-zero for step7's tail window).
#pragma unroll
  for (int k = lane; k < BUFSZ / 4; k += 64) {
    const int f = 4 * k - PAD;               // agent0 q-index of component .x
    f4 v = { 0.f, 0.f, 0.f, 0.f };
    if (f >= 0 && f + 3 < N_ATOM) {
      v.x = gp[f]; v.y = gp[f + 1]; v.z = gp[f + 2]; v.w = gp[f + 3];
    } else if (f + 3 >= 0 && f < N_ATOM) {
      if (f >= 0)                       v.x = gp[f];
      if (f + 1 >= 0 && f + 1 < N_ATOM) v.y = gp[f + 1];
      if (f + 2 >= 0 && f + 2 < N_ATOM) v.z = gp[f + 2];
      if (f + 3 < N_ATOM)               v.w = gp[f + 3];
    }
    *(volatile f4*)(b0 + 4 * k) = v;
  }
  // Init b1: left pad only (all other read regions of b1 are written by the
  // preceding step first: step5 R=8 covers [PAD,PAD+512) > max read 564).
  if (lane < PAD / 4) {
    f4 z = { 0.f, 0.f, 0.f, 0.f };
    *(volatile f4*)(b1 + 4 * lane) = z;
  }

  // L_out: 101,151,201,251 (R=4) ; 301,351 (R=8) ; 401 in registers (last)
  conv_step<4>(gp + 1 * N_ATOM, b0, b1, lane);
  conv_step<4>(gp + 2 * N_ATOM, b1, b0, lane);
  conv_step<4>(gp + 3 * N_ATOM, b0, b1, lane);
  conv_step<4>(gp + 4 * N_ATOM, b1, b0, lane);
  conv_step<8>(gp + 5 * N_ATOM, b0, b1, lane);
  conv_step<8>(gp + 6 * N_ATOM, b1, b0, lane);

  float acc[8];
  conv_body<8>(gp + 7 * N_ATOM, b0, acc, lane);

  // Projection epilogue; q beyond 400 is exact 0 so unguarded sums are safe.
  float s0 = 0.f, s1 = 0.f;
  float* o = out + (size_t)task * N_ATOM;
#pragma unroll
  for (int r = 0; r < 8; ++r) {
    const int oidx = 8 * lane + r;           // 0..511
    if (oidx >= 176 && oidx < 225) o[oidx - 175] = acc[r];
    s0 += (oidx < 176) ? acc[r] : 0.f;
    s1 += (oidx >= 225) ? acc[r] : 0.f;
  }
#pragma unroll
  for (int d = 1; d < 64; d <<= 1) {
    s0 += __shfl_xor(s0, d, 64);
    s1 += __shfl_xor(s1, d, 64);
  }
  if (lane == 0) { o[0] = s0; o[50] = s1; }
}

extern "C" void kernel_launch(void* const* d_in, const int* in_sizes, int n_in,
                              void* d_out, int out_size, void* d_ws, size_t ws_size,
                              hipStream_t stream) {
  const float* agent_qs = (const float*)d_in[0];  // [128,256,8,51] f32
  // d_in[1] (states) is unused by the reference computation
  float* out = (float*)d_out;                     // [128,256,51] f32
  dvdn_mixer_kernel<<<N_TASKS / WPB, 256, 0, stream>>>(agent_qs, out);
}